// Round 1
// 744.522 us; speedup vs baseline: 1.0458x; 1.0458x over previous
//
#include <hip/hip_runtime.h>
#include <hip/hip_bf16.h>

// Hierarchical BiGRU. Round 11 = round 10 + GRU step-pipeline:
//  - gru_mfma: gx loads for step t+1 issued before step t's MFMA chain
//    (addresses depend only on t). The 500-900cy L3/HBM latency that
//    previously stalled every step now hides under MFMA + gate math +
//    barrier. +6 VGPRs.
//  - sigf/tanh_fast: full-precision v_div sequences (no fast-math in
//    harness flags) replaced with single v_rcp_f32. ~150 wave-instrs/step
//    removed; rcp error ~1ulp << f16 storage rounding of h.
// gemm_mfma left untouched this round (attribution control).
// ws ~167 MB.

typedef __hip_bfloat16 bf16;
typedef _Float16 h16x8 __attribute__((ext_vector_type(8)));
typedef __fp16 fp16x2 __attribute__((ext_vector_type(2)));
typedef float f32x4 __attribute__((ext_vector_type(4)));

#define HDIM 200
#define NS   2560
#define TW   50
#define ND   256
#define DTR  10

#define GT   13          // tiles per gate (208 cols)
#define NT   39          // stored tiles (3 gates x 13)
#define NTP  40          // packed-B tiles for gemm (last = zero pad)
#define KCH  7           // W_hh k-chunks (200 -> 224)
#define HSTR 232         // h LDS row stride (halfs)
#define KC_W 10          // word x-proj k-chunks (300 -> 320)
#define KC_S 13          // sent x-proj k-chunks (400 -> 416)
#define EMB_ELEMS 15000000

__device__ __forceinline__ float sigf(float x) {
    // 1/(1+e^-x) via v_rcp_f32 (single instr; ~1ulp, << f16 rounding)
    return __builtin_amdgcn_rcpf(1.f + __expf(-x));
}
__device__ __forceinline__ float tanh_fast(float x) {
    float e = __expf(2.f * x);
    return (e - 1.f) * __builtin_amdgcn_rcpf(e + 1.f);
}
__device__ __forceinline__ unsigned short f2h(float x) {
    union { _Float16 h; unsigned short u; } v;
    v.h = (_Float16)x;
    return v.u;
}
__device__ __forceinline__ float h2f(unsigned short u) {
    union { _Float16 h; unsigned short u; } v;
    v.u = u;
    return (float)v.h;
}
// pack 2 f32 -> 2 f16 (RTZ, 1 instr), a low, b high
__device__ __forceinline__ unsigned pk2h(float a, float b) {
    union { fp16x2 p; unsigned u; } v;
    v.p = __builtin_amdgcn_cvt_pkrtz(a, b);
    return v.u;
}
// select f16 #rg (0..3) from a uint2 packed as (rg0,rg1 | rg2,rg3)
__device__ __forceinline__ float hfsel(uint2 v, int rg) {
    unsigned u = (rg & 2) ? v.y : v.x;
    return h2f((unsigned short)((rg & 1) ? (u >> 16) : (u & 0xFFFFu)));
}

// ---------------- sentence lengths ----------------
__global__ void lens_kernel(const int* __restrict__ x, int* __restrict__ sl) {
    int s = blockIdx.x * 256 + threadIdx.x;
    if (s < NS) {
        int c = 0;
        for (int t = 0; t < TW; ++t) c += (x[s * TW + t] != 0) ? 1 : 0;
        sl[s] = c;
    }
}

// ------------- pre-pack W_hh into per-gate-padded MFMA B-fragments (f16) --
__global__ void prepack_whh(const float* __restrict__ w0, const float* __restrict__ w1,
                            const float* __restrict__ w2, const float* __restrict__ w3,
                            unsigned short* __restrict__ Bp) {
    int gid = blockIdx.x * 256 + threadIdx.x;
    if (gid >= 4 * NT * KCH * 64) return;
    int lane = gid & 63;
    int f = gid >> 6;
    int kc = f % KCH;
    int tIdx = (f / KCH) % NT;
    int d = f / (KCH * NT);
    const float* w = (d == 0) ? w0 : (d == 1) ? w1 : (d == 2) ? w2 : w3;
    int g = tIdx / GT, j = tIdx % GT;
    int il = j * 16 + (lane & 15);
    int n = g * HDIM + il;
    int kb = kc * 32 + (lane >> 4) * 8;
    unsigned short vals[8] __attribute__((aligned(16)));
#pragma unroll
    for (int jj = 0; jj < 8; ++jj) {
        int k = kb + jj;
        float v = (il < HDIM && k < HDIM) ? w[n * HDIM + k] : 0.f;
        vals[jj] = f2h(v);
    }
    *reinterpret_cast<float4*>(reinterpret_cast<char*>(Bp) + (size_t)gid * 16) =
        *reinterpret_cast<const float4*>(vals);
}

// ------------- pre-pack W_ih into per-gate-padded B-fragments (f16) -------
__global__ void prepack_bih(const float* __restrict__ w, unsigned short* __restrict__ Bp,
                            int Kin, int KC) {
    int gid = blockIdx.x * 256 + threadIdx.x;
    if (gid >= NTP * KC * 64) return;
    int lane = gid & 63;
    int f = gid >> 6;
    int kc = f % KC;
    int tIdx = f / KC;
    int g = tIdx / GT, j = tIdx % GT;
    int il = j * 16 + (lane & 15);
    int n = g * HDIM + il;
    int kb = kc * 32 + (lane >> 4) * 8;
    unsigned short vals[8] __attribute__((aligned(16)));
#pragma unroll
    for (int jj = 0; jj < 8; ++jj) {
        int k = kb + jj;
        float v = (tIdx < NT && il < HDIM && k < Kin) ? w[n * Kin + k] : 0.f;
        vals[jj] = f2h(v);
    }
    *reinterpret_cast<float4*>(reinterpret_cast<char*>(Bp) + (size_t)gid * 16) =
        *reinterpret_cast<const float4*>(vals);
}

// ------------- per-column folded bias tables: bt[dir][624] ----------------
// col = g*208 + i: g<2 -> bi[g*200+i]+bh[g*200+i]; g==2 -> bi[400+i] (bh_n
// stays in the GRU, inside the r* term).
__global__ void prepack_bias(
    const float* bi0, const float* bh0, const float* bi1, const float* bh1,
    const float* bi2, const float* bh2, const float* bi3, const float* bh3,
    float* __restrict__ bt) {
    int gid = blockIdx.x * 256 + threadIdx.x;
    if (gid >= 4 * 624) return;
    int d = gid / 624, col = gid % 624;
    int g = col / 208, i = col % 208;
    const float* bi = (d == 0) ? bi0 : (d == 1) ? bi1 : (d == 2) ? bi2 : bi3;
    const float* bh = (d == 0) ? bh0 : (d == 1) ? bh1 : (d == 2) ? bh2 : bh3;
    float v = 0.f;
    if (i < HDIM) v = (g < 2) ? (bi[g * HDIM + i] + bh[g * HDIM + i]) : bi[2 * HDIM + i];
    bt[gid] = v;
}

// ---------------- MFMA GEMM (f16): gx_frag = A @ B + bt -------------------
// 512 thr / 8 waves: wave = (m_w = wv&1) x (n_w = wv>>1); wave covers
// 4 m-tiles x 10 n-tiles. Rows transposed: row' = t*S + s.
// GATHER: tok = idx[(row'%S)*Tseq + row'/S].
// Output f16 fragment layout: byte = ((gmt*39 + gnt)*64 + lane)*8 + reg*2.
template<bool GATHER>
__global__ __launch_bounds__(512, 2) void gemm_mfma(
    const float* __restrict__ Aemb, const float* __restrict__ Afl, int astride,
    const int* __restrict__ idx, int S, int Tseq,
    const unsigned short* __restrict__ Bp, int KC,
    const float* __restrict__ bt, unsigned short* __restrict__ gxOut)
{
    __shared__ __align__(16) unsigned short As[2][128 * 32];  // 16 KB dbuf
    __shared__ int toks[128];

    const int tid = threadIdx.x;
    const int wv = tid >> 6, lane = tid & 63;
    const int bm = blockIdx.x;
    const int m_w = wv & 1, n_w = wv >> 1;

    if (GATHER && tid < 128) {
        int rp = bm * 128 + tid;
        toks[tid] = idx[(rp % S) * Tseq + (rp / S)];
    }

    int aaddr[4];
#pragma unroll
    for (int mt = 0; mt < 4; ++mt) {
        int row = m_w * 64 + mt * 16 + (lane & 15);
        aaddr[mt] = row * 32 + (((lane >> 4) ^ ((row >> 1) & 3)) << 3);
    }

    // staging: thread -> (row srow, quarter qk); 8 f32 per thread per kc
    const int srow = tid >> 2, qk = tid & 3;
    const int ssw = (srow >> 1) & 3;

    f32x4 acc[4][10];
#pragma unroll
    for (int i = 0; i < 4; ++i)
#pragma unroll
        for (int j = 0; j < 10; ++j) acc[i][j] = (f32x4){0.f, 0.f, 0.f, 0.f};

    const uint4* bq = reinterpret_cast<const uint4*>(Bp);

    __syncthreads();  // toks visible
    const int obase = GATHER ? (toks[srow] * 300 + qk * 8) : 0;
    const float* arow = GATHER ? nullptr
        : Afl + (size_t)(bm * 128 + srow) * astride + qk * 8;

    float4 f[2], fn[2];
#pragma unroll
    for (int j = 0; j < 2; ++j) {
        if (GATHER) {
            int o = obase + j * 4;
            o = (o > EMB_ELEMS - 4) ? (EMB_ELEMS - 4) : o;
            f[j] = *reinterpret_cast<const float4*>(Aemb + o);
        } else {
            f[j] = *reinterpret_cast<const float4*>(arow + j * 4);
        }
    }

    for (int kc = 0; kc < KC; ++kc) {
        unsigned short* Ab = &As[kc & 1][0];
        {
            uint4 vh;
            vh.x = pk2h(f[0].x, f[0].y);
            vh.y = pk2h(f[0].z, f[0].w);
            vh.z = pk2h(f[1].x, f[1].y);
            vh.w = pk2h(f[1].z, f[1].w);
            int slot = qk ^ ssw;
            *reinterpret_cast<uint4*>(&Ab[srow * 32 + slot * 8]) = vh;
        }
        __syncthreads();

        // prefetch next A chunk (overlaps MFMA below)
        if (kc + 1 < KC) {
#pragma unroll
            for (int j = 0; j < 2; ++j) {
                if (GATHER) {
                    int o = obase + (kc + 1) * 32 + j * 4;
                    o = (o > EMB_ELEMS - 4) ? (EMB_ELEMS - 4) : o;
                    fn[j] = *reinterpret_cast<const float4*>(Aemb + o);
                } else {
                    fn[j] = *reinterpret_cast<const float4*>(arow + (kc + 1) * 32 + j * 4);
                }
            }
        }

        h16x8 ah[4];
#pragma unroll
        for (int mt = 0; mt < 4; ++mt)
            ah[mt] = *reinterpret_cast<const h16x8*>(&Ab[aaddr[mt]]);

        // two half-passes of 5 n-tiles to cap live B registers
#pragma unroll
        for (int half = 0; half < 2; ++half) {
            uint4 b[5];
#pragma unroll
            for (int j = 0; j < 5; ++j) {
                int gnt = n_w * 10 + half * 5 + j;
                b[j] = bq[(size_t)(gnt * KC + kc) * 64 + lane];
            }
#pragma unroll
            for (int mt = 0; mt < 4; ++mt)
#pragma unroll
                for (int j = 0; j < 5; ++j)
                    acc[mt][half * 5 + j] = __builtin_amdgcn_mfma_f32_16x16x32_f16(
                        ah[mt], *reinterpret_cast<const h16x8*>(&b[j]),
                        acc[mt][half * 5 + j], 0, 0, 0);
        }
        if (kc + 1 < KC) { f[0] = fn[0]; f[1] = fn[1]; }
    }

    // folded bias per column
    float btv[10];
#pragma unroll
    for (int j = 0; j < 10; ++j) {
        int gnt = n_w * 10 + j;
        btv[j] = (gnt < NT) ? bt[gnt * 16 + (lane & 15)] : 0.f;
    }

#pragma unroll
    for (int mt = 0; mt < 4; ++mt) {
        int gmt = bm * 8 + m_w * 4 + mt;
#pragma unroll
        for (int j = 0; j < 10; ++j) {
            int gnt = n_w * 10 + j;
            if (gnt < NT) {
                uint2 v;
                v.x = pk2h(acc[mt][j][0] + btv[j], acc[mt][j][1] + btv[j]);
                v.y = pk2h(acc[mt][j][2] + btv[j], acc[mt][j][3] + btv[j]);
                *reinterpret_cast<uint2*>(reinterpret_cast<char*>(gxOut) +
                    ((size_t)(gmt * NT + gnt) * 64 + lane) * 8) = v;
            }
        }
    }
}

// ---------------- MFMA GRU: f16, resident W_hh, 1 barrier/step -------------
// 832 thr / 13 waves, M=16 rows/block. Wave w owns within-gate tile w for
// ALL 3 gates: resident B = 21 frags = 84 VGPRs. Single f16 h (no hi/lo),
// double-buffered in LDS. In-register combine; gx coalesced dwordx2.
// R11: gx loads software-pipelined one step ahead (addresses depend only
// on t) so their L3/HBM latency hides under MFMA chain + gate math +
// barrier instead of stalling every step.
__global__ __launch_bounds__(832) void gru_mfma(
    const unsigned short* __restrict__ gx, const unsigned short* __restrict__ Bp,
    int dirBase, const float* __restrict__ bh,
    const int* __restrict__ lens, float* __restrict__ pool,
    int S, int T, int dirOff, int rev, int poolMode)
{
    __shared__ __align__(16) unsigned short hh[2][16 * HSTR];  // 14.5 KB

    const int tid = threadIdx.x;
    const int w = tid >> 6, lane = tid & 63;
    const int quad = lane >> 4, c = lane & 15;
    const int row0 = blockIdx.x * 16;
    const int i = w * 16 + c;
    const bool iv = (i < HDIM);

    for (int p = tid; p < 16 * HSTR; p += 832) { hh[0][p] = 0; hh[1][p] = 0; }

    const float bhn = iv ? bh[2 * HDIM + i] : 0.f;

    int slen[4];
    float hreg[4], pacc[4];
#pragma unroll
    for (int rg = 0; rg < 4; ++rg) {
        int L = lens[row0 + quad * 4 + rg];
        if (L < 0) L = 0;
        if (L > T) L = T;
        slen[rg] = L;
        hreg[rg] = 0.f; pacc[rg] = 0.f;
    }

    // resident B fragments: 3 gates x 7 k-chunks
    const float4* Bq = reinterpret_cast<const float4*>(Bp);
    h16x8 bfr[3][7];
#pragma unroll
    for (int g = 0; g < 3; ++g)
#pragma unroll
        for (int kc = 0; kc < KCH; ++kc) {
            int fidx = (dirBase + g * GT + w) * KCH + kc;
            float4 raw = Bq[(size_t)fidx * 64 + lane];
            bfr[g][kc] = *reinterpret_cast<h16x8*>(&raw);
        }

    const char* gxb = reinterpret_cast<const char*>(gx);
    const int am = c * HSTR + quad * 8;
    const int SG = S >> 4;
    const int hw0 = (quad * 4) * HSTR + i;
    __syncthreads();

    // preload gx for the first step
    uint2 gxv[3], gnx[3];
    {
        const int t0 = rev ? (T - 1) : 0;
        const long long gg = (long long)t0 * SG + blockIdx.x;
#pragma unroll
        for (int g = 0; g < 3; ++g)
            gxv[g] = *reinterpret_cast<const uint2*>(
                gxb + ((gg * NT + g * GT + w) * 64 + lane) * 8);
    }

    for (int ts = 0; ts < T; ++ts) {
        const int t = rev ? (T - 1 - ts) : ts;
        const int cur = ts & 1, nxt = cur ^ 1;

        // issue next step's gx loads first: latency hides under MFMA+gates
        if (ts + 1 < T) {
            const int tn = rev ? (T - 2 - ts) : (ts + 1);
            const long long gg = (long long)tn * SG + blockIdx.x;
#pragma unroll
            for (int g = 0; g < 3; ++g)
                gnx[g] = *reinterpret_cast<const uint2*>(
                    gxb + ((gg * NT + g * GT + w) * 64 + lane) * 8);
        }

        f32x4 a0 = (f32x4){0.f, 0.f, 0.f, 0.f}, a1 = a0, a2 = a0;
#pragma unroll
        for (int kc = 0; kc < KCH; ++kc) {
            h16x8 ah = *reinterpret_cast<const h16x8*>(&hh[cur][am + kc * 32]);
            a0 = __builtin_amdgcn_mfma_f32_16x16x32_f16(ah, bfr[0][kc], a0, 0, 0, 0);
            a1 = __builtin_amdgcn_mfma_f32_16x16x32_f16(ah, bfr[1][kc], a1, 0, 0, 0);
            a2 = __builtin_amdgcn_mfma_f32_16x16x32_f16(ah, bfr[2][kc], a2, 0, 0, 0);
        }

        if (iv) {
#pragma unroll
            for (int rg = 0; rg < 4; ++rg) {
                float xr = hfsel(gxv[0], rg);   // includes bi_r + bh_r
                float xz = hfsel(gxv[1], rg);   // includes bi_z + bh_z
                float xn = hfsel(gxv[2], rg);   // includes bi_n
                float r = sigf(xr + a0[rg]);
                float z = sigf(xz + a1[rg]);
                float n = tanh_fast(xn + r * (a2[rg] + bhn));
                float hnew = (1.f - z) * n + z * hreg[rg];
                hreg[rg] = hnew;
                hh[nxt][hw0 + rg * HSTR] = f2h(hnew);
                if (t < slen[rg]) pacc[rg] += hnew;
            }
        }
        __syncthreads();
        if (ts + 1 < T) {
#pragma unroll
            for (int g = 0; g < 3; ++g) gxv[g] = gnx[g];
        }
    }

    if (iv) {
#pragma unroll
        for (int rg = 0; rg < 4; ++rg) {
            int sg = row0 + quad * 4 + rg;
            int L = slen[rg];
            float v = (L > 0) ? pacc[rg] / (float)L : 0.f;
            int prow = poolMode ? ((sg % 10) * ND + sg / 10) : sg;
            pool[(size_t)prow * 400 + dirOff + i] = v;
        }
    }
}

// ---------------- heads: 256 blocks x 1 wave ----------------
__global__ __launch_bounds__(64) void head_kernel(
    const float* __restrict__ d_pool, const int* __restrict__ doc_lens,
    const float* __restrict__ doc_w, const float* __restrict__ doc_b,
    const float* __restrict__ sent_w, const float* __restrict__ sent_b,
    float* __restrict__ out)
{
    const int d = blockIdx.x;
    const int lane = threadIdx.x;

    int part = 0;
#pragma unroll
    for (int rep = 0; rep < 4; ++rep) {
        int j = lane + rep * 64;
        int v = doc_lens[j];
        v = (v < 0) ? 0 : (v > DTR ? DTR : v);
        if (j < d) part += v;
    }
#pragma unroll
    for (int off = 32; off; off >>= 1) part += __shfl_down(part, off);
    int soff = __shfl(part, 0);

    int dl = doc_lens[d];
    dl = (dl < 0) ? 0 : (dl > DTR ? DTR : dl);
    const float* dv = d_pool + (size_t)d * 400;

    for (int o = 0; o <= dl; ++o) {
        const float* wrow = (o == 0) ? doc_w : sent_w + (o - 1) * 400;
        float s = 0.f;
        for (int f = lane; f < 400; f += 64) s += dv[f] * wrow[f];
#pragma unroll
        for (int off = 32; off; off >>= 1) s += __shfl_down(s, off);
        if (lane == 0) {
            float bias = (o == 0) ? doc_b[0] : sent_b[o - 1];
            out[(o == 0) ? d : (ND + soff + (o - 1))] = sigf(s + bias);
        }
    }
}

// --------------------------------------------------------------------------
extern "C" void kernel_launch(void* const* d_in, const int* in_sizes, int n_in,
                              void* d_out, int out_size, void* d_ws, size_t ws_size,
                              hipStream_t stream) {
    const int*   x        = (const int*)d_in[0];
    const int*   doc_lens = (const int*)d_in[2];
    const float* emb      = (const float*)d_in[3];
    const float* wf_ih = (const float*)d_in[4];
    const float* wf_hh = (const float*)d_in[5];
    const float* wf_bi = (const float*)d_in[6];
    const float* wf_bh = (const float*)d_in[7];
    const float* wb_ih = (const float*)d_in[8];
    const float* wb_hh = (const float*)d_in[9];
    const float* wb_bi = (const float*)d_in[10];
    const float* wb_bh = (const float*)d_in[11];
    const float* sf_ih = (const float*)d_in[12];
    const float* sf_hh = (const float*)d_in[13];
    const float* sf_bi = (const float*)d_in[14];
    const float* sf_bh = (const float*)d_in[15];
    const float* sb_ih = (const float*)d_in[16];
    const float* sb_hh = (const float*)d_in[17];
    const float* sb_bi = (const float*)d_in[18];
    const float* sb_bh = (const float*)d_in[19];
    const float* doc_w  = (const float*)d_in[20];
    const float* doc_b  = (const float*)d_in[21];
    const float* sent_w = (const float*)d_in[22];
    const float* sent_b = (const float*)d_in[23];

    char* ws = (char*)d_ws;
    const size_t OFF_GX  = 0;                        // 8000*39*512 = 159,744,000
    const size_t OFF_SIN = 159744000;                // 2560*400*4 + 64B pad
    const size_t OFF_D   = OFF_SIN + 4096256;        // 256*400*4
    const size_t OFF_SL  = OFF_D + 409600;           // 2560*4
    const size_t OFF_BHH = OFF_SL + 10240;           // 4*39*7*1024 = 1,118,208
    const size_t OFF_BIW = OFF_BHH + 1118208;        // 2*40*10*1024 = 819,200
    const size_t OFF_BIS = OFF_BIW + 819200;         // 2*40*13*1024 = 1,064,960
    const size_t OFF_BT  = OFF_BIS + 1064960;        // 4*624*4 = 9,984
    unsigned short* gx   = (unsigned short*)(ws + OFF_GX);
    float* s_in   = (float*)(ws + OFF_SIN);
    float* dpool  = (float*)(ws + OFF_D);
    int*   sl     = (int*)(ws + OFF_SL);
    unsigned short* Bhh  = (unsigned short*)(ws + OFF_BHH);
    unsigned short* BiW0 = (unsigned short*)(ws + OFF_BIW);
    unsigned short* BiW1 = BiW0 + NTP * KC_W * 64 * 8;
    unsigned short* BiS0 = (unsigned short*)(ws + OFF_BIS);
    unsigned short* BiS1 = BiS0 + NTP * KC_S * 64 * 8;
    float* bt     = (float*)(ws + OFF_BT);  // 4 x 624

    prepack_whh<<<(4 * NT * KCH * 64 + 255) / 256, 256, 0, stream>>>(
        wf_hh, wb_hh, sf_hh, sb_hh, Bhh);
    prepack_bih<<<(NTP * KC_W * 64 + 255) / 256, 256, 0, stream>>>(wf_ih, BiW0, 300, KC_W);
    prepack_bih<<<(NTP * KC_W * 64 + 255) / 256, 256, 0, stream>>>(wb_ih, BiW1, 300, KC_W);
    prepack_bih<<<(NTP * KC_S * 64 + 255) / 256, 256, 0, stream>>>(sf_ih, BiS0, 400, KC_S);
    prepack_bih<<<(NTP * KC_S * 64 + 255) / 256, 256, 0, stream>>>(sb_ih, BiS1, 400, KC_S);
    prepack_bias<<<(4 * 624 + 255) / 256, 256, 0, stream>>>(
        wf_bi, wf_bh, wb_bi, wb_bh, sf_bi, sf_bh, sb_bi, sb_bh, bt);
    lens_kernel<<<(NS + 255) / 256, 256, 0, stream>>>(x, sl);

    // word level, forward
    gemm_mfma<true><<<1000, 512, 0, stream>>>(emb, nullptr, 0, x, NS, TW, BiW0, KC_W, bt + 0 * 624, gx);
    gru_mfma<<<NS / 16, 832, 0, stream>>>(gx, Bhh, 0 * NT, wf_bh, sl, s_in, NS, TW, 0, 0, 1);
    // word level, backward
    gemm_mfma<true><<<1000, 512, 0, stream>>>(emb, nullptr, 0, x, NS, TW, BiW1, KC_W, bt + 1 * 624, gx);
    gru_mfma<<<NS / 16, 832, 0, stream>>>(gx, Bhh, 1 * NT, wb_bh, sl, s_in, NS, TW, HDIM, 1, 1);
    // sentence level, forward (A = s_in, rows already transposed t*ND+d)
    gemm_mfma<false><<<20, 512, 0, stream>>>(nullptr, s_in, 400, nullptr, ND, DTR, BiS0, KC_S, bt + 2 * 624, gx);
    gru_mfma<<<ND / 16, 832, 0, stream>>>(gx, Bhh, 2 * NT, sf_bh, doc_lens, dpool, ND, DTR, 0, 0, 0);
    // sentence level, backward
    gemm_mfma<false><<<20, 512, 0, stream>>>(nullptr, s_in, 400, nullptr, ND, DTR, BiS1, KC_S, bt + 3 * 624, gx);
    gru_mfma<<<ND / 16, 832, 0, stream>>>(gx, Bhh, 3 * NT, sb_bh, doc_lens, dpool, ND, DTR, HDIM, 1, 0);

    head_kernel<<<ND, 64, 0, stream>>>(dpool, doc_lens, doc_w, doc_b, sent_w, sent_b, (float*)d_out);
}

// Round 2
// 707.668 us; speedup vs baseline: 1.1002x; 1.0521x over previous
//
#include <hip/hip_runtime.h>
#include <hip/hip_bf16.h>

// Hierarchical BiGRU. Round 12 = round 11 + word-gemm rewrite:
//  - prepack_embh: emb (50000x300 f32) -> embH (50000x320 f16, zero-padded)
//    once per launch. Same RTZ rounding as the old in-stage pk2h, so
//    numerics identical; halves gather bytes and removes staging converts.
//  - gemm_word (word level only): stages the whole 128x320 A-panel into
//    80 KB LDS with ONE barrier. Each thread issues its 10 uint4 gathers
//    back-to-back (10-deep MLP vs 1-deep prefetch before), then the
//    400-MFMA sweep runs barrier-free (B loads pipeline across kc).
//    Old structure stalled ~700cy/kc on the slowest-of-512 gather behind
//    a per-kc __syncthreads at 1 block/CU (280 unified regs -> 2 waves/SIMD).
//    XOR slot swizzle (slot ^ (row&7)) keeps LDS reads <=2-way (free).
//  - sentence gemm keeps the proven r10 template (control); GRU = r11.
// ws ~199 MB (embH +32 MB).

typedef __hip_bfloat16 bf16;
typedef _Float16 h16x8 __attribute__((ext_vector_type(8)));
typedef __fp16 fp16x2 __attribute__((ext_vector_type(2)));
typedef float f32x4 __attribute__((ext_vector_type(4)));

#define HDIM 200
#define NS   2560
#define TW   50
#define ND   256
#define DTR  10
#define VEMB 50000

#define GT   13          // tiles per gate (208 cols)
#define NT   39          // stored tiles (3 gates x 13)
#define NTP  40          // packed-B tiles for gemm (last = zero pad)
#define KCH  7           // W_hh k-chunks (200 -> 224)
#define HSTR 232         // h LDS row stride (halfs)
#define KC_W 10          // word x-proj k-chunks (300 -> 320)
#define KC_S 13          // sent x-proj k-chunks (400 -> 416)
#define EMB_ELEMS 15000000

__device__ __forceinline__ float sigf(float x) {
    return __builtin_amdgcn_rcpf(1.f + __expf(-x));
}
__device__ __forceinline__ float tanh_fast(float x) {
    float e = __expf(2.f * x);
    return (e - 1.f) * __builtin_amdgcn_rcpf(e + 1.f);
}
__device__ __forceinline__ unsigned short f2h(float x) {
    union { _Float16 h; unsigned short u; } v;
    v.h = (_Float16)x;
    return v.u;
}
__device__ __forceinline__ float h2f(unsigned short u) {
    union { _Float16 h; unsigned short u; } v;
    v.u = u;
    return (float)v.h;
}
// pack 2 f32 -> 2 f16 (RTZ, 1 instr), a low, b high
__device__ __forceinline__ unsigned pk2h(float a, float b) {
    union { fp16x2 p; unsigned u; } v;
    v.p = __builtin_amdgcn_cvt_pkrtz(a, b);
    return v.u;
}
// select f16 #rg (0..3) from a uint2 packed as (rg0,rg1 | rg2,rg3)
__device__ __forceinline__ float hfsel(uint2 v, int rg) {
    unsigned u = (rg & 2) ? v.y : v.x;
    return h2f((unsigned short)((rg & 1) ? (u >> 16) : (u & 0xFFFFu)));
}

// ---------------- sentence lengths ----------------
__global__ void lens_kernel(const int* __restrict__ x, int* __restrict__ sl) {
    int s = blockIdx.x * 256 + threadIdx.x;
    if (s < NS) {
        int c = 0;
        for (int t = 0; t < TW; ++t) c += (x[s * TW + t] != 0) ? 1 : 0;
        sl[s] = c;
    }
}

// ------------- emb f32 -> f16, rows padded 300 -> 320 ---------------------
// RTZ convert identical to the old in-stage pk2h: numerics unchanged.
__global__ void prepack_embh(const float* __restrict__ emb,
                             unsigned short* __restrict__ embH) {
    int gid = blockIdx.x * 256 + threadIdx.x;   // one per 8-half chunk
    if (gid >= VEMB * 40) return;               // 320/8 = 40 chunks/row
    int row = gid / 40, c = gid % 40;
    int k0 = c * 8;
    unsigned short vals[8] __attribute__((aligned(16)));
    if (k0 + 7 < 300) {
        const float4 f0 = *reinterpret_cast<const float4*>(emb + (size_t)row * 300 + k0);
        const float4 f1 = *reinterpret_cast<const float4*>(emb + (size_t)row * 300 + k0 + 4);
        unsigned u0 = pk2h(f0.x, f0.y), u1 = pk2h(f0.z, f0.w);
        unsigned u2 = pk2h(f1.x, f1.y), u3 = pk2h(f1.z, f1.w);
        vals[0] = (unsigned short)u0; vals[1] = (unsigned short)(u0 >> 16);
        vals[2] = (unsigned short)u1; vals[3] = (unsigned short)(u1 >> 16);
        vals[4] = (unsigned short)u2; vals[5] = (unsigned short)(u2 >> 16);
        vals[6] = (unsigned short)u3; vals[7] = (unsigned short)(u3 >> 16);
    } else {
#pragma unroll
        for (int jj = 0; jj < 8; ++jj) {
            int k = k0 + jj;
            vals[jj] = (k < 300) ? f2h(emb[(size_t)row * 300 + k]) : (unsigned short)0;
        }
    }
    *reinterpret_cast<uint4*>(embH + (size_t)gid * 8) =
        *reinterpret_cast<const uint4*>(vals);
}

// ------------- pre-pack W_hh into per-gate-padded MFMA B-fragments (f16) --
__global__ void prepack_whh(const float* __restrict__ w0, const float* __restrict__ w1,
                            const float* __restrict__ w2, const float* __restrict__ w3,
                            unsigned short* __restrict__ Bp) {
    int gid = blockIdx.x * 256 + threadIdx.x;
    if (gid >= 4 * NT * KCH * 64) return;
    int lane = gid & 63;
    int f = gid >> 6;
    int kc = f % KCH;
    int tIdx = (f / KCH) % NT;
    int d = f / (KCH * NT);
    const float* w = (d == 0) ? w0 : (d == 1) ? w1 : (d == 2) ? w2 : w3;
    int g = tIdx / GT, j = tIdx % GT;
    int il = j * 16 + (lane & 15);
    int n = g * HDIM + il;
    int kb = kc * 32 + (lane >> 4) * 8;
    unsigned short vals[8] __attribute__((aligned(16)));
#pragma unroll
    for (int jj = 0; jj < 8; ++jj) {
        int k = kb + jj;
        float v = (il < HDIM && k < HDIM) ? w[n * HDIM + k] : 0.f;
        vals[jj] = f2h(v);
    }
    *reinterpret_cast<float4*>(reinterpret_cast<char*>(Bp) + (size_t)gid * 16) =
        *reinterpret_cast<const float4*>(vals);
}

// ------------- pre-pack W_ih into per-gate-padded B-fragments (f16) -------
__global__ void prepack_bih(const float* __restrict__ w, unsigned short* __restrict__ Bp,
                            int Kin, int KC) {
    int gid = blockIdx.x * 256 + threadIdx.x;
    if (gid >= NTP * KC * 64) return;
    int lane = gid & 63;
    int f = gid >> 6;
    int kc = f % KC;
    int tIdx = f / KC;
    int g = tIdx / GT, j = tIdx % GT;
    int il = j * 16 + (lane & 15);
    int n = g * HDIM + il;
    int kb = kc * 32 + (lane >> 4) * 8;
    unsigned short vals[8] __attribute__((aligned(16)));
#pragma unroll
    for (int jj = 0; jj < 8; ++jj) {
        int k = kb + jj;
        float v = (tIdx < NT && il < HDIM && k < Kin) ? w[n * Kin + k] : 0.f;
        vals[jj] = f2h(v);
    }
    *reinterpret_cast<float4*>(reinterpret_cast<char*>(Bp) + (size_t)gid * 16) =
        *reinterpret_cast<const float4*>(vals);
}

// ------------- per-column folded bias tables: bt[dir][624] ----------------
__global__ void prepack_bias(
    const float* bi0, const float* bh0, const float* bi1, const float* bh1,
    const float* bi2, const float* bh2, const float* bi3, const float* bh3,
    float* __restrict__ bt) {
    int gid = blockIdx.x * 256 + threadIdx.x;
    if (gid >= 4 * 624) return;
    int d = gid / 624, col = gid % 624;
    int g = col / 208, i = col % 208;
    const float* bi = (d == 0) ? bi0 : (d == 1) ? bi1 : (d == 2) ? bi2 : bi3;
    const float* bh = (d == 0) ? bh0 : (d == 1) ? bh1 : (d == 2) ? bh2 : bh3;
    float v = 0.f;
    if (i < HDIM) v = (g < 2) ? (bi[g * HDIM + i] + bh[g * HDIM + i]) : bi[2 * HDIM + i];
    bt[gid] = v;
}

// ---------------- word-level MFMA GEMM: gx = embH[gather] @ B + bt --------
// 512 thr / 8 waves; wave = (m_w = wv&1) x (n_w = wv>>1), 4 mt x 10 nt.
// Whole 128x320 A-panel staged to LDS in one shot (10-deep load MLP per
// thread), ONE barrier, then barrier-free MFMA sweep. Rows transposed:
// row' = t*NS + s, tok = x[(row'%NS)*TW + row'/NS].
__global__ __launch_bounds__(512, 2) void gemm_word(
    const unsigned short* __restrict__ embH, const int* __restrict__ idx,
    const unsigned short* __restrict__ Bp,
    const float* __restrict__ bt, unsigned short* __restrict__ gxOut)
{
    __shared__ __align__(16) unsigned short As[128 * 320];  // 80 KB

    const int tid = threadIdx.x;
    const int wv = tid >> 6, lane = tid & 63;
    const int bm = blockIdx.x;
    const int m_w = wv & 1, n_w = wv >> 1;

    // ---- stage: gather 128 rows x 320 halfs -> LDS, one barrier ----
    {
        const int srow = tid >> 2, qk = tid & 3;
        int rp = bm * 128 + srow;
        int tok = idx[(rp % NS) * TW + (rp / NS)];
        const unsigned short* src = embH + (size_t)tok * 320 + qk * 8;
        uint4 v[KC_W];
#pragma unroll
        for (int kc = 0; kc < KC_W; ++kc)
            v[kc] = *reinterpret_cast<const uint4*>(src + kc * 32);
        const int rx = srow & 7;
        unsigned short* dst = &As[srow * 320];
#pragma unroll
        for (int kc = 0; kc < KC_W; ++kc) {
            int slot = (kc * 4 + qk) ^ rx;
            *reinterpret_cast<uint4*>(dst + slot * 8) = v[kc];
        }
    }
    __syncthreads();

    f32x4 acc[4][10];
#pragma unroll
    for (int i = 0; i < 4; ++i)
#pragma unroll
        for (int j = 0; j < 10; ++j) acc[i][j] = (f32x4){0.f, 0.f, 0.f, 0.f};

    const uint4* bq = reinterpret_cast<const uint4*>(Bp);
    const int q = lane >> 4;
    int abase[4], arx[4];
#pragma unroll
    for (int mt = 0; mt < 4; ++mt) {
        int row = m_w * 64 + mt * 16 + (lane & 15);
        abase[mt] = row * 320;
        arx[mt] = row & 7;
    }

#pragma unroll 2
    for (int kc = 0; kc < KC_W; ++kc) {
        h16x8 ah[4];
#pragma unroll
        for (int mt = 0; mt < 4; ++mt) {
            int slot = (kc * 4 + q) ^ arx[mt];
            ah[mt] = *reinterpret_cast<const h16x8*>(&As[abase[mt] + slot * 8]);
        }
#pragma unroll
        for (int half = 0; half < 2; ++half) {
            uint4 b[5];
#pragma unroll
            for (int j = 0; j < 5; ++j) {
                int gnt = n_w * 10 + half * 5 + j;
                b[j] = bq[(size_t)(gnt * KC_W + kc) * 64 + lane];
            }
#pragma unroll
            for (int mt = 0; mt < 4; ++mt)
#pragma unroll
                for (int j = 0; j < 5; ++j)
                    acc[mt][half * 5 + j] = __builtin_amdgcn_mfma_f32_16x16x32_f16(
                        ah[mt], *reinterpret_cast<const h16x8*>(&b[j]),
                        acc[mt][half * 5 + j], 0, 0, 0);
        }
    }

    // folded bias per column
    float btv[10];
#pragma unroll
    for (int j = 0; j < 10; ++j) {
        int gnt = n_w * 10 + j;
        btv[j] = (gnt < NT) ? bt[gnt * 16 + (lane & 15)] : 0.f;
    }

#pragma unroll
    for (int mt = 0; mt < 4; ++mt) {
        int gmt = bm * 8 + m_w * 4 + mt;
#pragma unroll
        for (int j = 0; j < 10; ++j) {
            int gnt = n_w * 10 + j;
            if (gnt < NT) {
                uint2 v;
                v.x = pk2h(acc[mt][j][0] + btv[j], acc[mt][j][1] + btv[j]);
                v.y = pk2h(acc[mt][j][2] + btv[j], acc[mt][j][3] + btv[j]);
                *reinterpret_cast<uint2*>(reinterpret_cast<char*>(gxOut) +
                    ((size_t)(gmt * NT + gnt) * 64 + lane) * 8) = v;
            }
        }
    }
}

// ---------------- sentence-level MFMA GEMM (r10 structure, f32 A) ---------
template<bool GATHER>
__global__ __launch_bounds__(512, 2) void gemm_mfma(
    const float* __restrict__ Aemb, const float* __restrict__ Afl, int astride,
    const int* __restrict__ idx, int S, int Tseq,
    const unsigned short* __restrict__ Bp, int KC,
    const float* __restrict__ bt, unsigned short* __restrict__ gxOut)
{
    __shared__ __align__(16) unsigned short As[2][128 * 32];  // 16 KB dbuf
    __shared__ int toks[128];

    const int tid = threadIdx.x;
    const int wv = tid >> 6, lane = tid & 63;
    const int bm = blockIdx.x;
    const int m_w = wv & 1, n_w = wv >> 1;

    if (GATHER && tid < 128) {
        int rp = bm * 128 + tid;
        toks[tid] = idx[(rp % S) * Tseq + (rp / S)];
    }

    int aaddr[4];
#pragma unroll
    for (int mt = 0; mt < 4; ++mt) {
        int row = m_w * 64 + mt * 16 + (lane & 15);
        aaddr[mt] = row * 32 + (((lane >> 4) ^ ((row >> 1) & 3)) << 3);
    }

    const int srow = tid >> 2, qk = tid & 3;
    const int ssw = (srow >> 1) & 3;

    f32x4 acc[4][10];
#pragma unroll
    for (int i = 0; i < 4; ++i)
#pragma unroll
        for (int j = 0; j < 10; ++j) acc[i][j] = (f32x4){0.f, 0.f, 0.f, 0.f};

    const uint4* bq = reinterpret_cast<const uint4*>(Bp);

    __syncthreads();  // toks visible
    const int obase = GATHER ? (toks[srow] * 300 + qk * 8) : 0;
    const float* arow = GATHER ? nullptr
        : Afl + (size_t)(bm * 128 + srow) * astride + qk * 8;

    float4 f[2], fn[2];
#pragma unroll
    for (int j = 0; j < 2; ++j) {
        if (GATHER) {
            int o = obase + j * 4;
            o = (o > EMB_ELEMS - 4) ? (EMB_ELEMS - 4) : o;
            f[j] = *reinterpret_cast<const float4*>(Aemb + o);
        } else {
            f[j] = *reinterpret_cast<const float4*>(arow + j * 4);
        }
    }

    for (int kc = 0; kc < KC; ++kc) {
        unsigned short* Ab = &As[kc & 1][0];
        {
            uint4 vh;
            vh.x = pk2h(f[0].x, f[0].y);
            vh.y = pk2h(f[0].z, f[0].w);
            vh.z = pk2h(f[1].x, f[1].y);
            vh.w = pk2h(f[1].z, f[1].w);
            int slot = qk ^ ssw;
            *reinterpret_cast<uint4*>(&Ab[srow * 32 + slot * 8]) = vh;
        }
        __syncthreads();

        if (kc + 1 < KC) {
#pragma unroll
            for (int j = 0; j < 2; ++j) {
                if (GATHER) {
                    int o = obase + (kc + 1) * 32 + j * 4;
                    o = (o > EMB_ELEMS - 4) ? (EMB_ELEMS - 4) : o;
                    fn[j] = *reinterpret_cast<const float4*>(Aemb + o);
                } else {
                    fn[j] = *reinterpret_cast<const float4*>(arow + (kc + 1) * 32 + j * 4);
                }
            }
        }

        h16x8 ah[4];
#pragma unroll
        for (int mt = 0; mt < 4; ++mt)
            ah[mt] = *reinterpret_cast<const h16x8*>(&Ab[aaddr[mt]]);

#pragma unroll
        for (int half = 0; half < 2; ++half) {
            uint4 b[5];
#pragma unroll
            for (int j = 0; j < 5; ++j) {
                int gnt = n_w * 10 + half * 5 + j;
                b[j] = bq[(size_t)(gnt * KC + kc) * 64 + lane];
            }
#pragma unroll
            for (int mt = 0; mt < 4; ++mt)
#pragma unroll
                for (int j = 0; j < 5; ++j)
                    acc[mt][half * 5 + j] = __builtin_amdgcn_mfma_f32_16x16x32_f16(
                        ah[mt], *reinterpret_cast<const h16x8*>(&b[j]),
                        acc[mt][half * 5 + j], 0, 0, 0);
        }
        if (kc + 1 < KC) { f[0] = fn[0]; f[1] = fn[1]; }
    }

    float btv[10];
#pragma unroll
    for (int j = 0; j < 10; ++j) {
        int gnt = n_w * 10 + j;
        btv[j] = (gnt < NT) ? bt[gnt * 16 + (lane & 15)] : 0.f;
    }

#pragma unroll
    for (int mt = 0; mt < 4; ++mt) {
        int gmt = bm * 8 + m_w * 4 + mt;
#pragma unroll
        for (int j = 0; j < 10; ++j) {
            int gnt = n_w * 10 + j;
            if (gnt < NT) {
                uint2 v;
                v.x = pk2h(acc[mt][j][0] + btv[j], acc[mt][j][1] + btv[j]);
                v.y = pk2h(acc[mt][j][2] + btv[j], acc[mt][j][3] + btv[j]);
                *reinterpret_cast<uint2*>(reinterpret_cast<char*>(gxOut) +
                    ((size_t)(gmt * NT + gnt) * 64 + lane) * 8) = v;
            }
        }
    }
}

// ---------------- MFMA GRU: f16, resident W_hh, 1 barrier/step -------------
// (r11: gx loads software-pipelined one step ahead; rcp-based gates.)
__global__ __launch_bounds__(832) void gru_mfma(
    const unsigned short* __restrict__ gx, const unsigned short* __restrict__ Bp,
    int dirBase, const float* __restrict__ bh,
    const int* __restrict__ lens, float* __restrict__ pool,
    int S, int T, int dirOff, int rev, int poolMode)
{
    __shared__ __align__(16) unsigned short hh[2][16 * HSTR];  // 14.5 KB

    const int tid = threadIdx.x;
    const int w = tid >> 6, lane = tid & 63;
    const int quad = lane >> 4, c = lane & 15;
    const int row0 = blockIdx.x * 16;
    const int i = w * 16 + c;
    const bool iv = (i < HDIM);

    for (int p = tid; p < 16 * HSTR; p += 832) { hh[0][p] = 0; hh[1][p] = 0; }

    const float bhn = iv ? bh[2 * HDIM + i] : 0.f;

    int slen[4];
    float hreg[4], pacc[4];
#pragma unroll
    for (int rg = 0; rg < 4; ++rg) {
        int L = lens[row0 + quad * 4 + rg];
        if (L < 0) L = 0;
        if (L > T) L = T;
        slen[rg] = L;
        hreg[rg] = 0.f; pacc[rg] = 0.f;
    }

    const float4* Bq = reinterpret_cast<const float4*>(Bp);
    h16x8 bfr[3][7];
#pragma unroll
    for (int g = 0; g < 3; ++g)
#pragma unroll
        for (int kc = 0; kc < KCH; ++kc) {
            int fidx = (dirBase + g * GT + w) * KCH + kc;
            float4 raw = Bq[(size_t)fidx * 64 + lane];
            bfr[g][kc] = *reinterpret_cast<h16x8*>(&raw);
        }

    const char* gxb = reinterpret_cast<const char*>(gx);
    const int am = c * HSTR + quad * 8;
    const int SG = S >> 4;
    const int hw0 = (quad * 4) * HSTR + i;
    __syncthreads();

    uint2 gxv[3], gnx[3];
    {
        const int t0 = rev ? (T - 1) : 0;
        const long long gg = (long long)t0 * SG + blockIdx.x;
#pragma unroll
        for (int g = 0; g < 3; ++g)
            gxv[g] = *reinterpret_cast<const uint2*>(
                gxb + ((gg * NT + g * GT + w) * 64 + lane) * 8);
    }

    for (int ts = 0; ts < T; ++ts) {
        const int t = rev ? (T - 1 - ts) : ts;
        const int cur = ts & 1, nxt = cur ^ 1;

        if (ts + 1 < T) {
            const int tn = rev ? (T - 2 - ts) : (ts + 1);
            const long long gg = (long long)tn * SG + blockIdx.x;
#pragma unroll
            for (int g = 0; g < 3; ++g)
                gnx[g] = *reinterpret_cast<const uint2*>(
                    gxb + ((gg * NT + g * GT + w) * 64 + lane) * 8);
        }

        f32x4 a0 = (f32x4){0.f, 0.f, 0.f, 0.f}, a1 = a0, a2 = a0;
#pragma unroll
        for (int kc = 0; kc < KCH; ++kc) {
            h16x8 ah = *reinterpret_cast<const h16x8*>(&hh[cur][am + kc * 32]);
            a0 = __builtin_amdgcn_mfma_f32_16x16x32_f16(ah, bfr[0][kc], a0, 0, 0, 0);
            a1 = __builtin_amdgcn_mfma_f32_16x16x32_f16(ah, bfr[1][kc], a1, 0, 0, 0);
            a2 = __builtin_amdgcn_mfma_f32_16x16x32_f16(ah, bfr[2][kc], a2, 0, 0, 0);
        }

        if (iv) {
#pragma unroll
            for (int rg = 0; rg < 4; ++rg) {
                float xr = hfsel(gxv[0], rg);
                float xz = hfsel(gxv[1], rg);
                float xn = hfsel(gxv[2], rg);
                float r = sigf(xr + a0[rg]);
                float z = sigf(xz + a1[rg]);
                float n = tanh_fast(xn + r * (a2[rg] + bhn));
                float hnew = (1.f - z) * n + z * hreg[rg];
                hreg[rg] = hnew;
                hh[nxt][hw0 + rg * HSTR] = f2h(hnew);
                if (t < slen[rg]) pacc[rg] += hnew;
            }
        }
        __syncthreads();
        if (ts + 1 < T) {
#pragma unroll
            for (int g = 0; g < 3; ++g) gxv[g] = gnx[g];
        }
    }

    if (iv) {
#pragma unroll
        for (int rg = 0; rg < 4; ++rg) {
            int sg = row0 + quad * 4 + rg;
            int L = slen[rg];
            float v = (L > 0) ? pacc[rg] / (float)L : 0.f;
            int prow = poolMode ? ((sg % 10) * ND + sg / 10) : sg;
            pool[(size_t)prow * 400 + dirOff + i] = v;
        }
    }
}

// ---------------- heads: 256 blocks x 1 wave ----------------
__global__ __launch_bounds__(64) void head_kernel(
    const float* __restrict__ d_pool, const int* __restrict__ doc_lens,
    const float* __restrict__ doc_w, const float* __restrict__ doc_b,
    const float* __restrict__ sent_w, const float* __restrict__ sent_b,
    float* __restrict__ out)
{
    const int d = blockIdx.x;
    const int lane = threadIdx.x;

    int part = 0;
#pragma unroll
    for (int rep = 0; rep < 4; ++rep) {
        int j = lane + rep * 64;
        int v = doc_lens[j];
        v = (v < 0) ? 0 : (v > DTR ? DTR : v);
        if (j < d) part += v;
    }
#pragma unroll
    for (int off = 32; off; off >>= 1) part += __shfl_down(part, off);
    int soff = __shfl(part, 0);

    int dl = doc_lens[d];
    dl = (dl < 0) ? 0 : (dl > DTR ? DTR : dl);
    const float* dv = d_pool + (size_t)d * 400;

    for (int o = 0; o <= dl; ++o) {
        const float* wrow = (o == 0) ? doc_w : sent_w + (o - 1) * 400;
        float s = 0.f;
        for (int f = lane; f < 400; f += 64) s += dv[f] * wrow[f];
#pragma unroll
        for (int off = 32; off; off >>= 1) s += __shfl_down(s, off);
        if (lane == 0) {
            float bias = (o == 0) ? doc_b[0] : sent_b[o - 1];
            out[(o == 0) ? d : (ND + soff + (o - 1))] = sigf(s + bias);
        }
    }
}

// --------------------------------------------------------------------------
extern "C" void kernel_launch(void* const* d_in, const int* in_sizes, int n_in,
                              void* d_out, int out_size, void* d_ws, size_t ws_size,
                              hipStream_t stream) {
    const int*   x        = (const int*)d_in[0];
    const int*   doc_lens = (const int*)d_in[2];
    const float* emb      = (const float*)d_in[3];
    const float* wf_ih = (const float*)d_in[4];
    const float* wf_hh = (const float*)d_in[5];
    const float* wf_bi = (const float*)d_in[6];
    const float* wf_bh = (const float*)d_in[7];
    const float* wb_ih = (const float*)d_in[8];
    const float* wb_hh = (const float*)d_in[9];
    const float* wb_bi = (const float*)d_in[10];
    const float* wb_bh = (const float*)d_in[11];
    const float* sf_ih = (const float*)d_in[12];
    const float* sf_hh = (const float*)d_in[13];
    const float* sf_bi = (const float*)d_in[14];
    const float* sf_bh = (const float*)d_in[15];
    const float* sb_ih = (const float*)d_in[16];
    const float* sb_hh = (const float*)d_in[17];
    const float* sb_bi = (const float*)d_in[18];
    const float* sb_bh = (const float*)d_in[19];
    const float* doc_w  = (const float*)d_in[20];
    const float* doc_b  = (const float*)d_in[21];
    const float* sent_w = (const float*)d_in[22];
    const float* sent_b = (const float*)d_in[23];

    char* ws = (char*)d_ws;
    const size_t OFF_GX  = 0;                        // 8000*39*512 = 159,744,000
    const size_t OFF_SIN = 159744000;                // 2560*400*4 + 64B pad
    const size_t OFF_D   = OFF_SIN + 4096256;        // 256*400*4
    const size_t OFF_SL  = OFF_D + 409600;           // 2560*4
    const size_t OFF_BHH = OFF_SL + 10240;           // 4*39*7*1024 = 1,118,208
    const size_t OFF_BIW = OFF_BHH + 1118208;        // 2*40*10*1024 = 819,200
    const size_t OFF_BIS = OFF_BIW + 819200;         // 2*40*13*1024 = 1,064,960
    const size_t OFF_BT  = OFF_BIS + 1064960;        // 4*624*4 = 9,984
    const size_t OFF_EMBH = OFF_BT + 9984;           // 50000*320*2 = 32,000,000
    unsigned short* gx   = (unsigned short*)(ws + OFF_GX);
    float* s_in   = (float*)(ws + OFF_SIN);
    float* dpool  = (float*)(ws + OFF_D);
    int*   sl     = (int*)(ws + OFF_SL);
    unsigned short* Bhh  = (unsigned short*)(ws + OFF_BHH);
    unsigned short* BiW0 = (unsigned short*)(ws + OFF_BIW);
    unsigned short* BiW1 = BiW0 + NTP * KC_W * 64 * 8;
    unsigned short* BiS0 = (unsigned short*)(ws + OFF_BIS);
    unsigned short* BiS1 = BiS0 + NTP * KC_S * 64 * 8;
    float* bt     = (float*)(ws + OFF_BT);  // 4 x 624
    unsigned short* embH = (unsigned short*)(ws + OFF_EMBH);

    prepack_embh<<<(VEMB * 40 + 255) / 256, 256, 0, stream>>>(emb, embH);
    prepack_whh<<<(4 * NT * KCH * 64 + 255) / 256, 256, 0, stream>>>(
        wf_hh, wb_hh, sf_hh, sb_hh, Bhh);
    prepack_bih<<<(NTP * KC_W * 64 + 255) / 256, 256, 0, stream>>>(wf_ih, BiW0, 300, KC_W);
    prepack_bih<<<(NTP * KC_W * 64 + 255) / 256, 256, 0, stream>>>(wb_ih, BiW1, 300, KC_W);
    prepack_bih<<<(NTP * KC_S * 64 + 255) / 256, 256, 0, stream>>>(sf_ih, BiS0, 400, KC_S);
    prepack_bih<<<(NTP * KC_S * 64 + 255) / 256, 256, 0, stream>>>(sb_ih, BiS1, 400, KC_S);
    prepack_bias<<<(4 * 624 + 255) / 256, 256, 0, stream>>>(
        wf_bi, wf_bh, wb_bi, wb_bh, sf_bi, sf_bh, sb_bi, sb_bh, bt);
    lens_kernel<<<(NS + 255) / 256, 256, 0, stream>>>(x, sl);

    // word level, forward
    gemm_word<<<1000, 512, 0, stream>>>(embH, x, BiW0, bt + 0 * 624, gx);
    gru_mfma<<<NS / 16, 832, 0, stream>>>(gx, Bhh, 0 * NT, wf_bh, sl, s_in, NS, TW, 0, 0, 1);
    // word level, backward
    gemm_word<<<1000, 512, 0, stream>>>(embH, x, BiW1, bt + 1 * 624, gx);
    gru_mfma<<<NS / 16, 832, 0, stream>>>(gx, Bhh, 1 * NT, wb_bh, sl, s_in, NS, TW, HDIM, 1, 1);
    // sentence level, forward (A = s_in, rows already transposed t*ND+d)
    gemm_mfma<false><<<20, 512, 0, stream>>>(nullptr, s_in, 400, nullptr, ND, DTR, BiS0, KC_S, bt + 2 * 624, gx);
    gru_mfma<<<ND / 16, 832, 0, stream>>>(gx, Bhh, 2 * NT, sf_bh, doc_lens, dpool, ND, DTR, 0, 0, 0);
    // sentence level, backward
    gemm_mfma<false><<<20, 512, 0, stream>>>(nullptr, s_in, 400, nullptr, ND, DTR, BiS1, KC_S, bt + 3 * 624, gx);
    gru_mfma<<<ND / 16, 832, 0, stream>>>(gx, Bhh, 3 * NT, sb_bh, doc_lens, dpool, ND, DTR, HDIM, 1, 0);

    head_kernel<<<ND, 64, 0, stream>>>(dpool, doc_lens, doc_w, doc_b, sent_w, sent_b, (float*)d_out);
}

// Round 5
// 686.252 us; speedup vs baseline: 1.1346x; 1.0312x over previous
//
#include <hip/hip_runtime.h>
#include <hip/hip_bf16.h>

// Hierarchical BiGRU. Round 15 = round 13 design, clean resubmission.
//  - gru_fused: fwd+bwd recurrences in ONE dispatch (320 blocks word /
//    32 sent). Two independent 13-wave blocks co-reside per CU (64 VGPR,
//    14.5 KB LDS -> 2 blocks fit; __launch_bounds__(832,8) pins VGPR<=64),
//    filling each other's idle issue slots and using all 256 CUs.
//  - gemm_word_fused / gemm_sent: both directions in one dispatch.
//  - prepacks merged. Dispatches 16 -> 9. ws ~359 MB fused, ~199 MB fallback.

typedef __hip_bfloat16 bf16;
typedef _Float16 h16x8 __attribute__((ext_vector_type(8)));
typedef __fp16 fp16x2 __attribute__((ext_vector_type(2)));
typedef float f32x4 __attribute__((ext_vector_type(4)));

#define HDIM 200
#define NS   2560
#define TW   50
#define ND   256
#define DTR  10
#define VEMB 50000

#define GT   13
#define NT   39
#define NTP  40
#define KCH  7
#define HSTR 232
#define KC_W 10
#define KC_S 13

__device__ __forceinline__ float sigf(float x) {
    return __builtin_amdgcn_rcpf(1.f + __expf(-x));
}
__device__ __forceinline__ float tanh_fast(float x) {
    float e = __expf(2.f * x);
    return (e - 1.f) * __builtin_amdgcn_rcpf(e + 1.f);
}
__device__ __forceinline__ unsigned short f2h(float x) {
    union { _Float16 h; unsigned short u; } v;
    v.h = (_Float16)x;
    return v.u;
}
__device__ __forceinline__ float h2f(unsigned short u) {
    union { _Float16 h; unsigned short u; } v;
    v.u = u;
    return (float)v.h;
}
__device__ __forceinline__ unsigned pk2h(float a, float b) {
    union { fp16x2 p; unsigned u; } v;
    v.p = __builtin_amdgcn_cvt_pkrtz(a, b);
    return v.u;
}
__device__ __forceinline__ float hfsel(uint2 v, int rg) {
    unsigned u = (rg & 2) ? v.y : v.x;
    return h2f((unsigned short)((rg & 1) ? (u >> 16) : (u & 0xFFFFu)));
}

// ------------- emb f32 -> f16, rows padded 300 -> 320 ---------------------
__global__ void prepack_embh(const float* __restrict__ emb,
                             unsigned short* __restrict__ embH) {
    int gid = blockIdx.x * 256 + threadIdx.x;
    if (gid >= VEMB * 40) return;
    int row = gid / 40, c = gid % 40;
    int k0 = c * 8;
    unsigned short vals[8] __attribute__((aligned(16)));
    if (k0 + 7 < 300) {
        const float4 f0 = *reinterpret_cast<const float4*>(emb + (size_t)row * 300 + k0);
        const float4 f1 = *reinterpret_cast<const float4*>(emb + (size_t)row * 300 + k0 + 4);
        unsigned u0 = pk2h(f0.x, f0.y), u1 = pk2h(f0.z, f0.w);
        unsigned u2 = pk2h(f1.x, f1.y), u3 = pk2h(f1.z, f1.w);
        vals[0] = (unsigned short)u0; vals[1] = (unsigned short)(u0 >> 16);
        vals[2] = (unsigned short)u1; vals[3] = (unsigned short)(u1 >> 16);
        vals[4] = (unsigned short)u2; vals[5] = (unsigned short)(u2 >> 16);
        vals[6] = (unsigned short)u3; vals[7] = (unsigned short)(u3 >> 16);
    } else {
#pragma unroll
        for (int jj = 0; jj < 8; ++jj) {
            int k = k0 + jj;
            vals[jj] = (k < 300) ? f2h(emb[(size_t)row * 300 + k]) : (unsigned short)0;
        }
    }
    *reinterpret_cast<uint4*>(embH + (size_t)gid * 8) =
        *reinterpret_cast<const uint4*>(vals);
}

// ------------- pre-pack W_hh into per-gate-padded MFMA B-fragments (f16) --
__global__ void prepack_whh(const float* __restrict__ w0, const float* __restrict__ w1,
                            const float* __restrict__ w2, const float* __restrict__ w3,
                            unsigned short* __restrict__ Bp) {
    int gid = blockIdx.x * 256 + threadIdx.x;
    if (gid >= 4 * NT * KCH * 64) return;
    int lane = gid & 63;
    int f = gid >> 6;
    int kc = f % KCH;
    int tIdx = (f / KCH) % NT;
    int d = f / (KCH * NT);
    const float* w = (d == 0) ? w0 : (d == 1) ? w1 : (d == 2) ? w2 : w3;
    int g = tIdx / GT, j = tIdx % GT;
    int il = j * 16 + (lane & 15);
    int n = g * HDIM + il;
    int kb = kc * 32 + (lane >> 4) * 8;
    unsigned short vals[8] __attribute__((aligned(16)));
#pragma unroll
    for (int jj = 0; jj < 8; ++jj) {
        int k = kb + jj;
        float v = (il < HDIM && k < HDIM) ? w[n * HDIM + k] : 0.f;
        vals[jj] = f2h(v);
    }
    *reinterpret_cast<float4*>(reinterpret_cast<char*>(Bp) + (size_t)gid * 16) =
        *reinterpret_cast<const float4*>(vals);
}

// ------------- pre-pack all four W_ih in one dispatch ---------------------
__global__ void prepack_bih_all(
    const float* __restrict__ w0, const float* __restrict__ w1,
    const float* __restrict__ w2, const float* __restrict__ w3,
    unsigned short* __restrict__ B0, unsigned short* __restrict__ B1,
    unsigned short* __restrict__ B2, unsigned short* __restrict__ B3) {
    int b = blockIdx.x;
    const float* w; unsigned short* Bp; int Kin, KC, base;
    if (b < 100)      { w = w0; Bp = B0; Kin = 300; KC = KC_W; base = 0; }
    else if (b < 200) { w = w1; Bp = B1; Kin = 300; KC = KC_W; base = 100; }
    else if (b < 330) { w = w2; Bp = B2; Kin = 400; KC = KC_S; base = 200; }
    else              { w = w3; Bp = B3; Kin = 400; KC = KC_S; base = 330; }
    int gid = (b - base) * 256 + threadIdx.x;
    if (gid >= NTP * KC * 64) return;
    int lane = gid & 63;
    int f = gid >> 6;
    int kc = f % KC;
    int tIdx = f / KC;
    int g = tIdx / GT, j = tIdx % GT;
    int il = j * 16 + (lane & 15);
    int n = g * HDIM + il;
    int kb = kc * 32 + (lane >> 4) * 8;
    unsigned short vals[8] __attribute__((aligned(16)));
#pragma unroll
    for (int jj = 0; jj < 8; ++jj) {
        int k = kb + jj;
        float v = (tIdx < NT && il < HDIM && k < Kin) ? w[n * Kin + k] : 0.f;
        vals[jj] = f2h(v);
    }
    *reinterpret_cast<float4*>(reinterpret_cast<char*>(Bp) + (size_t)gid * 16) =
        *reinterpret_cast<const float4*>(vals);
}

// ------------- lens + folded bias tables in one dispatch ------------------
__global__ void prepack_small(
    const int* __restrict__ x, int* __restrict__ sl,
    const float* bi0, const float* bh0, const float* bi1, const float* bh1,
    const float* bi2, const float* bh2, const float* bi3, const float* bh3,
    float* __restrict__ bt) {
    int gid = blockIdx.x * 256 + threadIdx.x;
    if (gid < NS) {
        int c = 0;
        for (int t = 0; t < TW; ++t) c += (x[gid * TW + t] != 0) ? 1 : 0;
        sl[gid] = c;
        return;
    }
    int g2 = gid - NS;
    if (g2 >= 4 * 624) return;
    int d = g2 / 624, col = g2 % 624;
    int g = col / 208, i = col % 208;
    const float* bi = (d == 0) ? bi0 : (d == 1) ? bi1 : (d == 2) ? bi2 : bi3;
    const float* bh = (d == 0) ? bh0 : (d == 1) ? bh1 : (d == 2) ? bh2 : bh3;
    float v = 0.f;
    if (i < HDIM) v = (g < 2) ? (bi[g * HDIM + i] + bh[g * HDIM + i]) : bi[2 * HDIM + i];
    bt[g2] = v;
}

// ---------------- word-level MFMA GEMM, both directions -------------------
// blocks [0,nF) -> dir0, [nF,grid) -> dir1. Per block: 128x320 A-panel
// staged to 80 KB LDS with ONE barrier, then barrier-free MFMA sweep.
__global__ __launch_bounds__(512, 2) void gemm_word_fused(
    const unsigned short* __restrict__ embH, const int* __restrict__ idx,
    const unsigned short* __restrict__ Bp0, const unsigned short* __restrict__ Bp1,
    const float* __restrict__ bt0, const float* __restrict__ bt1,
    unsigned short* __restrict__ gx0, unsigned short* __restrict__ gx1, int nF)
{
    __shared__ __align__(16) unsigned short As[128 * 320];  // 80 KB

    const int tid = threadIdx.x;
    const int wv = tid >> 6, lane = tid & 63;
    const int d = (blockIdx.x >= nF) ? 1 : 0;
    const int bm = d ? (blockIdx.x - nF) : blockIdx.x;
    const unsigned short* Bp = d ? Bp1 : Bp0;
    const float* bt = d ? bt1 : bt0;
    unsigned short* gxOut = d ? gx1 : gx0;
    const int m_w = wv & 1, n_w = wv >> 1;

    {
        const int srow = tid >> 2, qk = tid & 3;
        int rp = bm * 128 + srow;
        int tok = idx[(rp % NS) * TW + (rp / NS)];
        const unsigned short* src = embH + (size_t)tok * 320 + qk * 8;
        uint4 v[KC_W];
#pragma unroll
        for (int kc = 0; kc < KC_W; ++kc)
            v[kc] = *reinterpret_cast<const uint4*>(src + kc * 32);
        const int rx = srow & 7;
        unsigned short* dst = &As[srow * 320];
#pragma unroll
        for (int kc = 0; kc < KC_W; ++kc) {
            int slot = (kc * 4 + qk) ^ rx;
            *reinterpret_cast<uint4*>(dst + slot * 8) = v[kc];
        }
    }
    __syncthreads();

    f32x4 acc[4][10];
#pragma unroll
    for (int i = 0; i < 4; ++i)
#pragma unroll
        for (int j = 0; j < 10; ++j) acc[i][j] = (f32x4){0.f, 0.f, 0.f, 0.f};

    const uint4* bq = reinterpret_cast<const uint4*>(Bp);
    const int q = lane >> 4;
    int abase[4], arx[4];
#pragma unroll
    for (int mt = 0; mt < 4; ++mt) {
        int row = m_w * 64 + mt * 16 + (lane & 15);
        abase[mt] = row * 320;
        arx[mt] = row & 7;
    }

#pragma unroll 2
    for (int kc = 0; kc < KC_W; ++kc) {
        h16x8 ah[4];
#pragma unroll
        for (int mt = 0; mt < 4; ++mt) {
            int slot = (kc * 4 + q) ^ arx[mt];
            ah[mt] = *reinterpret_cast<const h16x8*>(&As[abase[mt] + slot * 8]);
        }
#pragma unroll
        for (int half = 0; half < 2; ++half) {
            uint4 b[5];
#pragma unroll
            for (int j = 0; j < 5; ++j) {
                int gnt = n_w * 10 + half * 5 + j;
                b[j] = bq[(size_t)(gnt * KC_W + kc) * 64 + lane];
            }
#pragma unroll
            for (int mt = 0; mt < 4; ++mt)
#pragma unroll
                for (int j = 0; j < 5; ++j)
                    acc[mt][half * 5 + j] = __builtin_amdgcn_mfma_f32_16x16x32_f16(
                        ah[mt], *reinterpret_cast<const h16x8*>(&b[j]),
                        acc[mt][half * 5 + j], 0, 0, 0);
        }
    }

    float btv[10];
#pragma unroll
    for (int j = 0; j < 10; ++j) {
        int gnt = n_w * 10 + j;
        btv[j] = (gnt < NT) ? bt[gnt * 16 + (lane & 15)] : 0.f;
    }

#pragma unroll
    for (int mt = 0; mt < 4; ++mt) {
        int gmt = bm * 8 + m_w * 4 + mt;
#pragma unroll
        for (int j = 0; j < 10; ++j) {
            int gnt = n_w * 10 + j;
            if (gnt < NT) {
                uint2 v;
                v.x = pk2h(acc[mt][j][0] + btv[j], acc[mt][j][1] + btv[j]);
                v.y = pk2h(acc[mt][j][2] + btv[j], acc[mt][j][3] + btv[j]);
                *reinterpret_cast<uint2*>(reinterpret_cast<char*>(gxOut) +
                    ((size_t)(gmt * NT + gnt) * 64 + lane) * 8) = v;
            }
        }
    }
}

// ---------------- sentence-level MFMA GEMM, both directions (f32 A) -------
__global__ __launch_bounds__(512, 2) void gemm_sent(
    const float* __restrict__ Afl, int astride,
    const unsigned short* __restrict__ Bp0, const unsigned short* __restrict__ Bp1,
    const float* __restrict__ bt0, const float* __restrict__ bt1,
    unsigned short* __restrict__ gx0, unsigned short* __restrict__ gx1, int nF)
{
    __shared__ __align__(16) unsigned short As[2][128 * 32];  // 16 KB dbuf

    const int tid = threadIdx.x;
    const int wv = tid >> 6, lane = tid & 63;
    const int d = (blockIdx.x >= nF) ? 1 : 0;
    const int bm = d ? (blockIdx.x - nF) : blockIdx.x;
    const unsigned short* Bp = d ? Bp1 : Bp0;
    const float* bt = d ? bt1 : bt0;
    unsigned short* gxOut = d ? gx1 : gx0;
    const int m_w = wv & 1, n_w = wv >> 1;

    int aaddr[4];
#pragma unroll
    for (int mt = 0; mt < 4; ++mt) {
        int row = m_w * 64 + mt * 16 + (lane & 15);
        aaddr[mt] = row * 32 + (((lane >> 4) ^ ((row >> 1) & 3)) << 3);
    }

    const int srow = tid >> 2, qk = tid & 3;
    const int ssw = (srow >> 1) & 3;

    f32x4 acc[4][10];
#pragma unroll
    for (int i = 0; i < 4; ++i)
#pragma unroll
        for (int j = 0; j < 10; ++j) acc[i][j] = (f32x4){0.f, 0.f, 0.f, 0.f};

    const uint4* bq = reinterpret_cast<const uint4*>(Bp);
    const float* arow = Afl + (size_t)(bm * 128 + srow) * astride + qk * 8;

    float4 f[2], fn[2];
#pragma unroll
    for (int j = 0; j < 2; ++j)
        f[j] = *reinterpret_cast<const float4*>(arow + j * 4);

    for (int kc = 0; kc < KC_S; ++kc) {
        unsigned short* Ab = &As[kc & 1][0];
        {
            uint4 vh;
            vh.x = pk2h(f[0].x, f[0].y);
            vh.y = pk2h(f[0].z, f[0].w);
            vh.z = pk2h(f[1].x, f[1].y);
            vh.w = pk2h(f[1].z, f[1].w);
            int slot = qk ^ ssw;
            *reinterpret_cast<uint4*>(&Ab[srow * 32 + slot * 8]) = vh;
        }
        __syncthreads();

        if (kc + 1 < KC_S) {
#pragma unroll
            for (int j = 0; j < 2; ++j)
                fn[j] = *reinterpret_cast<const float4*>(arow + (kc + 1) * 32 + j * 4);
        }

        h16x8 ah[4];
#pragma unroll
        for (int mt = 0; mt < 4; ++mt)
            ah[mt] = *reinterpret_cast<const h16x8*>(&Ab[aaddr[mt]]);

#pragma unroll
        for (int half = 0; half < 2; ++half) {
            uint4 b[5];
#pragma unroll
            for (int j = 0; j < 5; ++j) {
                int gnt = n_w * 10 + half * 5 + j;
                b[j] = bq[(size_t)(gnt * KC_S + kc) * 64 + lane];
            }
#pragma unroll
            for (int mt = 0; mt < 4; ++mt)
#pragma unroll
                for (int j = 0; j < 5; ++j)
                    acc[mt][half * 5 + j] = __builtin_amdgcn_mfma_f32_16x16x32_f16(
                        ah[mt], *reinterpret_cast<const h16x8*>(&b[j]),
                        acc[mt][half * 5 + j], 0, 0, 0);
        }
        if (kc + 1 < KC_S) { f[0] = fn[0]; f[1] = fn[1]; }
    }

    float btv[10];
#pragma unroll
    for (int j = 0; j < 10; ++j) {
        int gnt = n_w * 10 + j;
        btv[j] = (gnt < NT) ? bt[gnt * 16 + (lane & 15)] : 0.f;
    }

#pragma unroll
    for (int mt = 0; mt < 4; ++mt) {
        int gmt = bm * 8 + m_w * 4 + mt;
#pragma unroll
        for (int j = 0; j < 10; ++j) {
            int gnt = n_w * 10 + j;
            if (gnt < NT) {
                uint2 v;
                v.x = pk2h(acc[mt][j][0] + btv[j], acc[mt][j][1] + btv[j]);
                v.y = pk2h(acc[mt][j][2] + btv[j], acc[mt][j][3] + btv[j]);
                *reinterpret_cast<uint2*>(reinterpret_cast<char*>(gxOut) +
                    ((size_t)(gmt * NT + gnt) * 64 + lane) * 8) = v;
            }
        }
    }
}

// ---------------- MFMA GRU, both directions in one dispatch ---------------
// blocks [0,nF) -> dir0 (fwd), [nF,grid) -> dir1 (bwd, rev, dirOff=HDIM).
__global__ __launch_bounds__(832, 8) void gru_fused(
    const unsigned short* __restrict__ gxA, const unsigned short* __restrict__ gxB,
    const unsigned short* __restrict__ Bp, int dirBase0, int dirBase1,
    const float* __restrict__ bh0, const float* __restrict__ bh1,
    const int* __restrict__ lens, float* __restrict__ pool,
    int S, int T, int poolMode, int nF)
{
    __shared__ __align__(16) unsigned short hh[2][16 * HSTR];  // 14.5 KB

    const int dsel = (blockIdx.x >= nF) ? 1 : 0;
    const int lb = dsel ? (blockIdx.x - nF) : blockIdx.x;
    const unsigned short* gx = dsel ? gxB : gxA;
    const int dirBase = dsel ? dirBase1 : dirBase0;
    const float* bh = dsel ? bh1 : bh0;
    const int dirOff = dsel ? HDIM : 0;
    const int rev = dsel;

    const int tid = threadIdx.x;
    const int w = tid >> 6, lane = tid & 63;
    const int quad = lane >> 4, c = lane & 15;
    const int row0 = lb * 16;
    const int i = w * 16 + c;
    const bool iv = (i < HDIM);

    for (int p = tid; p < 16 * HSTR; p += 832) { hh[0][p] = 0; hh[1][p] = 0; }

    const float bhn = iv ? bh[2 * HDIM + i] : 0.f;

    int slen[4];
    float hreg[4], pacc[4];
#pragma unroll
    for (int rg = 0; rg < 4; ++rg) {
        int L = lens[row0 + quad * 4 + rg];
        if (L < 0) L = 0;
        if (L > T) L = T;
        slen[rg] = L;
        hreg[rg] = 0.f; pacc[rg] = 0.f;
    }

    const float4* Bq = reinterpret_cast<const float4*>(Bp);
    h16x8 bfr[3][7];
#pragma unroll
    for (int g = 0; g < 3; ++g)
#pragma unroll
        for (int kc = 0; kc < KCH; ++kc) {
            int fidx = (dirBase + g * GT + w) * KCH + kc;
            float4 raw = Bq[(size_t)fidx * 64 + lane];
            bfr[g][kc] = *reinterpret_cast<h16x8*>(&raw);
        }

    const char* gxb = reinterpret_cast<const char*>(gx);
    const int am = c * HSTR + quad * 8;
    const int SG = S >> 4;
    const int hw0 = (quad * 4) * HSTR + i;
    __syncthreads();

    uint2 gxv[3], gnx[3];
    {
        const int t0 = rev ? (T - 1) : 0;
        const long long gg = (long long)t0 * SG + lb;
#pragma unroll
        for (int g = 0; g < 3; ++g)
            gxv[g] = *reinterpret_cast<const uint2*>(
                gxb + ((gg * NT + g * GT + w) * 64 + lane) * 8);
    }

    for (int ts = 0; ts < T; ++ts) {
        const int t = rev ? (T - 1 - ts) : ts;
        const int cur = ts & 1, nxt = cur ^ 1;

        if (ts + 1 < T) {
            const int tn = rev ? (T - 2 - ts) : (ts + 1);
            const long long gg = (long long)tn * SG + lb;
#pragma unroll
            for (int g = 0; g < 3; ++g)
                gnx[g] = *reinterpret_cast<const uint2*>(
                    gxb + ((gg * NT + g * GT + w) * 64 + lane) * 8);
        }

        f32x4 a0 = (f32x4){0.f, 0.f, 0.f, 0.f}, a1 = a0, a2 = a0;
#pragma unroll
        for (int kc = 0; kc < KCH; ++kc) {
            h16x8 ah = *reinterpret_cast<const h16x8*>(&hh[cur][am + kc * 32]);
            a0 = __builtin_amdgcn_mfma_f32_16x16x32_f16(ah, bfr[0][kc], a0, 0, 0, 0);
            a1 = __builtin_amdgcn_mfma_f32_16x16x32_f16(ah, bfr[1][kc], a1, 0, 0, 0);
            a2 = __builtin_amdgcn_mfma_f32_16x16x32_f16(ah, bfr[2][kc], a2, 0, 0, 0);
        }

        if (iv) {
#pragma unroll
            for (int rg = 0; rg < 4; ++rg) {
                float xr = hfsel(gxv[0], rg);
                float xz = hfsel(gxv[1], rg);
                float xn = hfsel(gxv[2], rg);
                float r = sigf(xr + a0[rg]);
                float z = sigf(xz + a1[rg]);
                float n = tanh_fast(xn + r * (a2[rg] + bhn));
                float hnew = (1.f - z) * n + z * hreg[rg];
                hreg[rg] = hnew;
                hh[nxt][hw0 + rg * HSTR] = f2h(hnew);
                if (t < slen[rg]) pacc[rg] += hnew;
            }
        }
        __syncthreads();
        if (ts + 1 < T) {
#pragma unroll
            for (int g = 0; g < 3; ++g) gxv[g] = gnx[g];
        }
    }

    if (iv) {
#pragma unroll
        for (int rg = 0; rg < 4; ++rg) {
            int sg = row0 + quad * 4 + rg;
            int L = slen[rg];
            float v = (L > 0) ? pacc[rg] / (float)L : 0.f;
            int prow = poolMode ? ((sg % 10) * ND + sg / 10) : sg;
            pool[(size_t)prow * 400 + dirOff + i] = v;
        }
    }
}

// ---------------- heads: 256 blocks x 1 wave ----------------
__global__ __launch_bounds__(64) void head_kernel(
    const float* __restrict__ d_pool, const int* __restrict__ doc_lens,
    const float* __restrict__ doc_w, const float* __restrict__ doc_b,
    const float* __restrict__ sent_w, const float* __restrict__ sent_b,
    float* __restrict__ out)
{
    const int d = blockIdx.x;
    const int lane = threadIdx.x;

    int part = 0;
#pragma unroll
    for (int rep = 0; rep < 4; ++rep) {
        int j = lane + rep * 64;
        int v = doc_lens[j];
        v = (v < 0) ? 0 : (v > DTR ? DTR : v);
        if (j < d) part += v;
    }
#pragma unroll
    for (int off = 32; off; off >>= 1) part += __shfl_down(part, off);
    int soff = __shfl(part, 0);

    int dl = doc_lens[d];
    dl = (dl < 0) ? 0 : (dl > DTR ? DTR : dl);
    const float* dv = d_pool + (size_t)d * 400;

    for (int o = 0; o <= dl; ++o) {
        const float* wrow = (o == 0) ? doc_w : sent_w + (o - 1) * 400;
        float s = 0.f;
        for (int f = lane; f < 400; f += 64) s += dv[f] * wrow[f];
#pragma unroll
        for (int off = 32; off; off >>= 1) s += __shfl_down(s, off);
        if (lane == 0) {
            float bias = (o == 0) ? doc_b[0] : sent_b[o - 1];
            out[(o == 0) ? d : (ND + soff + (o - 1))] = sigf(s + bias);
        }
    }
}

// --------------------------------------------------------------------------
extern "C" void kernel_launch(void* const* d_in, const int* in_sizes, int n_in,
                              void* d_out, int out_size, void* d_ws, size_t ws_size,
                              hipStream_t stream) {
    const int*   x        = (const int*)d_in[0];
    const int*   doc_lens = (const int*)d_in[2];
    const float* emb      = (const float*)d_in[3];
    const float* wf_ih = (const float*)d_in[4];
    const float* wf_hh = (const float*)d_in[5];
    const float* wf_bi = (const float*)d_in[6];
    const float* wf_bh = (const float*)d_in[7];
    const float* wb_ih = (const float*)d_in[8];
    const float* wb_hh = (const float*)d_in[9];
    const float* wb_bi = (const float*)d_in[10];
    const float* wb_bh = (const float*)d_in[11];
    const float* sf_ih = (const float*)d_in[12];
    const float* sf_hh = (const float*)d_in[13];
    const float* sf_bi = (const float*)d_in[14];
    const float* sf_bh = (const float*)d_in[15];
    const float* sb_ih = (const float*)d_in[16];
    const float* sb_hh = (const float*)d_in[17];
    const float* sb_bi = (const float*)d_in[18];
    const float* sb_bh = (const float*)d_in[19];
    const float* doc_w  = (const float*)d_in[20];
    const float* doc_b  = (const float*)d_in[21];
    const float* sent_w = (const float*)d_in[22];
    const float* sent_b = (const float*)d_in[23];

    const size_t GXSZ = 159744000;   // 8000*39*512 bytes
    const size_t restSz = 4096256 + 409600 + 10240 + 1118208 + 819200
                        + 1064960 + 9984 + 32000000;   // 39,528,448
    char* ws = (char*)d_ws;
    const bool fused = (ws_size == 0) || (ws_size >= 2 * GXSZ + restSz);

    const size_t gxbOff = fused ? GXSZ : 0;
    const size_t base   = gxbOff + GXSZ;
    unsigned short* gxA = (unsigned short*)(ws);
    unsigned short* gxB = (unsigned short*)(ws + gxbOff);  // == gxA when !fused
    float* s_in   = (float*)(ws + base);                       // 4,096,256 B
    float* dpool  = (float*)(ws + base + 4096256);             // 409,600 B
    int*   sl     = (int*)(ws + base + 4096256 + 409600);      // 10,240 B
    unsigned short* Bhh  = (unsigned short*)(ws + base + 4096256 + 409600 + 10240);
    unsigned short* BiW0 = (unsigned short*)((char*)Bhh + 1118208);
    unsigned short* BiW1 = BiW0 + NTP * KC_W * 64 * 8;
    unsigned short* BiS0 = (unsigned short*)((char*)BiW0 + 819200);
    unsigned short* BiS1 = BiS0 + NTP * KC_S * 64 * 8;
    float* bt     = (float*)((char*)BiS0 + 1064960);  // 4 x 624 floats
    unsigned short* embH = (unsigned short*)((char*)bt + 9984);  // 32,000,000 B

    prepack_embh<<<(VEMB * 40 + 255) / 256, 256, 0, stream>>>(emb, embH);
    prepack_whh<<<(4 * NT * KCH * 64 + 255) / 256, 256, 0, stream>>>(
        wf_hh, wb_hh, sf_hh, sb_hh, Bhh);
    prepack_bih_all<<<460, 256, 0, stream>>>(
        wf_ih, wb_ih, sf_ih, sb_ih, BiW0, BiW1, BiS0, BiS1);
    prepack_small<<<(NS + 4 * 624 + 255) / 256, 256, 0, stream>>>(
        x, sl, wf_bi, wf_bh, wb_bi, wb_bh, sf_bi, sf_bh, sb_bi, sb_bh, bt);

    if (fused) {
        gemm_word_fused<<<2000, 512, 0, stream>>>(
            embH, x, BiW0, BiW1, bt + 0, bt + 624, gxA, gxB, 1000);
        gru_fused<<<320, 832, 0, stream>>>(
            gxA, gxB, Bhh, 0 * NT, 1 * NT, wf_bh, wb_bh, sl, s_in, NS, TW, 1, 160);
        gemm_sent<<<40, 512, 0, stream>>>(
            s_in, 400, BiS0, BiS1, bt + 2 * 624, bt + 3 * 624, gxA, gxB, 20);
        gru_fused<<<32, 832, 0, stream>>>(
            gxA, gxB, Bhh, 2 * NT, 3 * NT, sf_bh, sb_bh, doc_lens, dpool, ND, DTR, 0, 16);
    } else {
        // sequential fallback: single gx buffer (r12 schedule)
        gemm_word_fused<<<1000, 512, 0, stream>>>(
            embH, x, BiW0, BiW1, bt + 0, bt + 624, gxA, gxA, 1000);
        gru_fused<<<160, 832, 0, stream>>>(
            gxA, gxA, Bhh, 0 * NT, 1 * NT, wf_bh, wb_bh, sl, s_in, NS, TW, 1, 160);
        gemm_word_fused<<<1000, 512, 0, stream>>>(
            embH, x, BiW0, BiW1, bt + 0, bt + 624, gxA, gxA, 0);
        gru_fused<<<160, 832, 0, stream>>>(
            gxA, gxA, Bhh, 0 * NT, 1 * NT, wf_bh, wb_bh, sl, s_in, NS, TW, 1, 0);
        gemm_sent<<<20, 512, 0, stream>>>(
            s_in, 400, BiS0, BiS1, bt + 2 * 624, bt + 3 * 624, gxA, gxA, 20);
        gru_fused<<<16, 832, 0, stream>>>(
            gxA, gxA, Bhh, 2 * NT, 3 * NT, sf_bh, sb_bh, doc_lens, dpool, ND, DTR, 0, 16);
        gemm_sent<<<20, 512, 0, stream>>>(
            s_in, 400, BiS0, BiS1, bt + 2 * 624, bt + 3 * 624, gxA, gxA, 0);
        gru_fused<<<16, 832, 0, stream>>>(
            gxA, gxA, Bhh, 2 * NT, 3 * NT, sf_bh, sb_bh, doc_lens, dpool, ND, DTR, 0, 0);
    }

    head_kernel<<<ND, 64, 0, stream>>>(dpool, doc_lens, doc_w, doc_b, sent_w, sent_b, (float*)d_out);
}